// Round 1
// baseline (94.009 us; speedup 1.0000x reference)
//
#include <hip/hip_runtime.h>
#include <math.h>

typedef __attribute__((ext_vector_type(8))) short s16x8;
typedef __attribute__((ext_vector_type(4))) float f32x4;
typedef __attribute__((ext_vector_type(16))) float f32x16;

#define BATCH 2
#define CH    64
#define NI    32
#define NPTS  8000
#define KSPLIT 10
#define TPS   25       // tiles (32 keys) per split: 250/10
#define XS_PITCH 68    // fp32 LDS pitch
#define EL_PITCH 68
#define LOG2E 1.4426950408889634f

// ---- workspace layout ----
// ushort indices from (ushort*)ws:
#define QB_U  0                        // [b][n][32] q bf16
#define KB_U  (BATCH*NPTS*NI)          // [b][n][32] k~ = log2e*k bf16
#define VB_U  (2*BATCH*NPTS*NI)        // [b][c][n]  v bf16
// float indices from (float*)ws:
#define ATT_F  1024000                 // [b][c][k] energy (atomic) (8192)
#define OUTP_F (ATT_F + BATCH*CH*CH)   // [b][c][n] flash accumulator
#define SUMP_F (OUTP_F + BATCH*CH*NPTS)        // [b][n] softmax denom
#define WS_END (SUMP_F + BATCH*NPTS)
#define ZERO_PER_BLK 4160              // (BATCH*CH*NPTS+BATCH*NPTS)/250 exact

__device__ __forceinline__ unsigned short f2bf(float f) {
  unsigned int u = __float_as_uint(f);
  return (unsigned short)((u + 0x7fffu + ((u >> 16) & 1u)) >> 16);
}

__device__ __forceinline__ float fexp2(float x) {
  return __builtin_amdgcn_exp2f(x);    // v_exp_f32 (computes 2^x natively)
}

__device__ __forceinline__ unsigned int cvt_pk_bf16(float lo, float hi) {
  unsigned int r;
  asm("v_cvt_pk_bf16_f32 %0, %1, %2" : "=v"(r) : "v"(lo), "v"(hi));
  return r;
}

__device__ __forceinline__ s16x8 frag_lds(const float* p) {
  float4 a = *(const float4*)p;
  float4 b = *(const float4*)(p + 4);
  union { unsigned int ui[4]; s16x8 v; } r;
  r.ui[0] = cvt_pk_bf16(a.x, a.y);
  r.ui[1] = cvt_pk_bf16(a.z, a.w);
  r.ui[2] = cvt_pk_bf16(b.x, b.y);
  r.ui[3] = cvt_pk_bf16(b.z, b.w);
  return r.v;
}

// x-fragment: lane -> (n = nt*16 + (l&15), c = ks*32 + (l>>4)*8 + j).
// Serves as A-frag for D[n][i] (q/k) AND B-frag for D[c][n] (v).
__device__ __forceinline__ s16x8 xfrag_make(const float* xs, int nt, int ks, int l) {
  const float* p = xs + (ks * 32 + (l >> 4) * 8) * XS_PITCH + nt * 16 + (l & 15);
  union { unsigned int ui[4]; s16x8 v; } r;
  r.ui[0] = cvt_pk_bf16(p[0 * XS_PITCH], p[1 * XS_PITCH]);
  r.ui[1] = cvt_pk_bf16(p[2 * XS_PITCH], p[3 * XS_PITCH]);
  r.ui[2] = cvt_pk_bf16(p[4 * XS_PITCH], p[5 * XS_PITCH]);
  r.ui[3] = cvt_pk_bf16(p[6 * XS_PITCH], p[7 * XS_PITCH]);
  return r.v;
}

// W-fragment: lane -> (row = (l&15) of Wrow-strip, k = ks*32 + (l>>4)*8 + j);
// contiguous 32B per lane. B-frag for q/k (col=i), A-frag for v (row=c_out).
__device__ __forceinline__ s16x8 wfrag_make(const float* W, int i0, int ks, int l) {
  const float* p = W + (size_t)(i0 + (l & 15)) * CH + ks * 32 + (l >> 4) * 8;
  float4 a = *(const float4*)p;
  float4 b = *(const float4*)(p + 4);
  union { unsigned int ui[4]; s16x8 v; } r;
  r.ui[0] = cvt_pk_bf16(a.x, a.y);
  r.ui[1] = cvt_pk_bf16(a.z, a.w);
  r.ui[2] = cvt_pk_bf16(b.x, b.y);
  r.ui[3] = cvt_pk_bf16(b.z, b.w);
  return r.v;
}

// ---------------- K1: MFMA qkv projections + Gram energy + OUTP zeroing -----
// 8 waves. Projection via MFMA: waves 0,1 -> q rows; 2,3 -> k~; 4-7 -> v.
// Then waves 0-3 do the Gram partial, waves 4-7 zero the flash accumulators.
__global__ __launch_bounds__(512) void qkv_energy_kernel(
    const float* __restrict__ x,
    const float* __restrict__ Wq, const float* __restrict__ bq,
    const float* __restrict__ Wk, const float* __restrict__ bk,
    const float* __restrict__ Wv, const float* __restrict__ bv,
    float* __restrict__ ws) {
  __shared__ float xs[CH * XS_PITCH];
  int tid = threadIdx.x, l = tid & 63, w = tid >> 6;
  int b = blockIdx.y;
  int n0 = blockIdx.x * 64;
  const float* xb = x + (size_t)b * CH * NPTS;
  {
    int c = tid >> 3, col = (tid & 7) * 8;
    const float* src = xb + (size_t)c * NPTS + n0 + col;
    float4 a0 = *(const float4*)src;
    float4 a1 = *(const float4*)(src + 4);
    *(float4*)&xs[c * XS_PITCH + col] = a0;
    *(float4*)&xs[c * XS_PITCH + col + 4] = a1;
  }
  __syncthreads();
  unsigned short* u = (unsigned short*)ws;
  const f32x4 fz4 = {0.f, 0.f, 0.f, 0.f};

  if (w < 4) {
    // ---- q (w0,w1) / k~ (w2,w3): D[n][i] = x^T W^T ----
    bool isq = (w < 2);
    const float* W  = isq ? Wq : Wk;
    const float* bi = isq ? bq : bk;
    float scl = isq ? 1.f : LOG2E;
    int i0 = (w & 1) * 16;
    int i = i0 + (l & 15);
    float bias = bi[i];
    s16x8 wf0 = wfrag_make(W, i0, 0, l);
    s16x8 wf1 = wfrag_make(W, i0, 1, l);
    unsigned short* dst = u + (isq ? QB_U : KB_U) + (size_t)b * NPTS * NI;
#pragma unroll
    for (int nt = 0; nt < 4; ++nt) {
      s16x8 xf0 = xfrag_make(xs, nt, 0, l);
      s16x8 xf1 = xfrag_make(xs, nt, 1, l);
      f32x4 acc = __builtin_amdgcn_mfma_f32_16x16x32_bf16(xf0, wf0, fz4, 0, 0, 0);
      acc = __builtin_amdgcn_mfma_f32_16x16x32_bf16(xf1, wf1, acc, 0, 0, 0);
#pragma unroll
      for (int r = 0; r < 4; ++r) {
        int n = n0 + nt * 16 + (l >> 4) * 4 + r;
        dst[(size_t)n * NI + i] = f2bf((acc[r] + bias) * scl);
      }
    }
  } else {
    // ---- v (w4-7): D[c][n] = Wv x ----
    int c0 = (w - 4) * 16;
    s16x8 wf0 = wfrag_make(Wv, c0, 0, l);
    s16x8 wf1 = wfrag_make(Wv, c0, 1, l);
    float bv4[4];
#pragma unroll
    for (int r = 0; r < 4; ++r) bv4[r] = bv[c0 + (l >> 4) * 4 + r];
    unsigned short* vdst = u + VB_U + (size_t)b * CH * NPTS;
#pragma unroll
    for (int nt = 0; nt < 4; ++nt) {
      s16x8 xf0 = xfrag_make(xs, nt, 0, l);
      s16x8 xf1 = xfrag_make(xs, nt, 1, l);
      f32x4 acc = __builtin_amdgcn_mfma_f32_16x16x32_bf16(wf0, xf0, fz4, 0, 0, 0);
      acc = __builtin_amdgcn_mfma_f32_16x16x32_bf16(wf1, xf1, acc, 0, 0, 0);
      int n = n0 + nt * 16 + (l & 15);
#pragma unroll
      for (int r = 0; r < 4; ++r) {
        int c = c0 + (l >> 4) * 4 + r;
        vdst[(size_t)c * NPTS + n] = f2bf(acc[r] + bv4[r]);
      }
    }
  }

  if (w < 4) {
    // ---- Gram partial for this 64-n chunk -> atomicAdd into energy ----
    int w2 = w;
    int rsel = l & 15, ksel = (l >> 4) * 8;
    f32x4 acc0 = {0.f,0.f,0.f,0.f}, acc1 = acc0, acc2 = acc0, acc3 = acc0;
#pragma unroll
    for (int ks = 0; ks < 2; ++ks) {
      int kb2 = ks * 32 + ksel;
      s16x8 f0 = frag_lds(&xs[(0  + rsel) * XS_PITCH + kb2]);
      s16x8 f1 = frag_lds(&xs[(16 + rsel) * XS_PITCH + kb2]);
      s16x8 f2 = frag_lds(&xs[(32 + rsel) * XS_PITCH + kb2]);
      s16x8 f3 = frag_lds(&xs[(48 + rsel) * XS_PITCH + kb2]);
      s16x8 fa = (w2 == 0) ? f0 : (w2 == 1) ? f1 : (w2 == 2) ? f2 : f3;
      acc0 = __builtin_amdgcn_mfma_f32_16x16x32_bf16(fa, f0, acc0, 0, 0, 0);
      acc1 = __builtin_amdgcn_mfma_f32_16x16x32_bf16(fa, f1, acc1, 0, 0, 0);
      acc2 = __builtin_amdgcn_mfma_f32_16x16x32_bf16(fa, f2, acc2, 0, 0, 0);
      acc3 = __builtin_amdgcn_mfma_f32_16x16x32_bf16(fa, f3, acc3, 0, 0, 0);
    }
    float* att = ws + ATT_F + (size_t)b * CH * CH;
    int r0 = 16 * w2 + (l >> 4) * 4, cl = l & 15;
#pragma unroll
    for (int r = 0; r < 4; ++r) {
      atomicAdd(&att[(r0 + r) * CH +  0 + cl], acc0[r]);
      atomicAdd(&att[(r0 + r) * CH + 16 + cl], acc1[r]);
      atomicAdd(&att[(r0 + r) * CH + 32 + cl], acc2[r]);
      atomicAdd(&att[(r0 + r) * CH + 48 + cl], acc3[r]);
    }
  } else {
    // ---- zero OUTP+SUMP slice (flash atomics need zeroed dst each launch) --
    int id = blockIdx.y * 125 + blockIdx.x;
    float* z = ws + OUTP_F + (size_t)id * ZERO_PER_BLK;
    int t2 = tid - 256;
    float4 z4 = {0.f, 0.f, 0.f, 0.f};
#pragma unroll
    for (int s = t2; s < ZERO_PER_BLK / 4; s += 256)
      *(float4*)(z + (size_t)s * 4) = z4;
  }
}

// ---------------- K2: 32x32 MFMA flash ------------------------------------
// One wave = 32 q-rows x all 64 d. Per 32-key tile per wave:
//   2 MFMA (QK, K=32 via two 32x32x16) -> 16 exp2 -> 8 cvt_pk -> 4 MFMA (PV).
// Denominator by VALU tree-sum per lane + one shfl_xor(32) at the end
// (frees the ones-MFMA). P B-frag key order {0-3,8-11,..}+4*hi is matched by
// key-granule-shuffling V during staging (register-level swap of 8B granules
// 1<->2 and 5<->6 per 32-key row) -- zero-cost, no cross-lane ops in loop.
__global__ __launch_bounds__(128, 3) void flash_kernel(
    float* __restrict__ ws) {
  __shared__ unsigned short Kls[2][32 * 32];   // [key][d], row-XOR-swizzled
  __shared__ unsigned short Vls[2][64 * 32];   // [d][key-pos], swizzled+shuffled

  int tid = threadIdx.x, l = tid & 63, wv = tid >> 6;
  int hi = l >> 5, r = l & 31;
  int ks = blockIdx.y, b = blockIdx.z;
  int q = blockIdx.x * 64 + wv * 32 + r;
  int key0 = ks * TPS * 32;

  const unsigned short* u = (const unsigned short*)ws;
  const unsigned short* qb = u + QB_U + (size_t)b * NPTS * NI;
  const unsigned short* kb = u + KB_U + (size_t)b * NPTS * NI;
  const unsigned short* vb = u + VB_U + (size_t)b * CH * NPTS;

  // Q B-frags: lane holds Q[q][d = hi*8 + j] (and +16 for 2nd k-step)
  s16x8 qf0 = *(const s16x8*)(qb + (size_t)q * NI + hi * 8);
  s16x8 qf1 = *(const s16x8*)(qb + (size_t)q * NI + 16 + hi * 8);

  // staging: K 2KB = 128 thr x 16B; V 4KB = 128 thr x 32B
  int kkey = tid >> 2, kdc = tid & 3;
  int ke = (kkey * 32 + kdc * 8) ^ ((kkey & 7) << 3);
  const unsigned short* ksrc = kb + (size_t)(key0 + kkey) * NI + kdc * 8;
  int vd = tid >> 1, vh = tid & 1;
  int ve1 = (vd * 32 + vh * 16) ^ ((vd & 7) << 3);
  int ve2 = (vd * 32 + vh * 16 + 8) ^ ((vd & 7) << 3);
  const unsigned short* vsrc = vb + (size_t)vd * NPTS + key0 + vh * 16;

  // in-loop fragment read addresses (elements)
  int sw = (r & 7) << 3;
  int ka0 = (r * 32 + hi * 8) ^ sw;
  int ka1 = (r * 32 + 16 + hi * 8) ^ sw;
  int va00 = (r * 32 + hi * 8) ^ sw;                 // d 0-31,  keys 0-15
  int va01 = (r * 32 + 16 + hi * 8) ^ sw;            // d 0-31,  keys 16-31
  int va10 = ((32 + r) * 32 + hi * 8) ^ sw;          // d 32-63, keys 0-15
  int va11 = ((32 + r) * 32 + 16 + hi * 8) ^ sw;     // d 32-63, keys 16-31

  f32x16 accA, accB, z16;
#pragma unroll
  for (int i = 0; i < 16; ++i) { accA[i] = 0.f; accB[i] = 0.f; z16[i] = 0.f; }
  float dsum = 0.f;

  uint4 kld = *(const uint4*)ksrc;
  uint4 vA = *(const uint4*)vsrc;
  uint4 vB = *(const uint4*)(vsrc + 8);
  *(uint4*)&Kls[0][ke] = kld;
  *(uint4*)&Vls[0][ve1] = make_uint4(vA.x, vA.y, vB.x, vB.y);  // granules 0,2
  *(uint4*)&Vls[0][ve2] = make_uint4(vA.z, vA.w, vB.z, vB.w);  // granules 1,3

  for (int t = 0; t < TPS; ++t) {
    __syncthreads();
    int buf = t & 1;
    bool pre = (t + 1 < TPS);
    if (pre) {                                   // issue next-tile loads early
      kld = *(const uint4*)(ksrc + (size_t)(t + 1) * 32 * NI);
      vA = *(const uint4*)(vsrc + (size_t)(t + 1) * 32);
      vB = *(const uint4*)(vsrc + (size_t)(t + 1) * 32 + 8);
    }
    s16x8 kf0 = *(const s16x8*)&Kls[buf][ka0];
    s16x8 kf1 = *(const s16x8*)&Kls[buf][ka1];
    f32x16 s = __builtin_amdgcn_mfma_f32_32x32x16_bf16(kf0, qf0, z16, 0, 0, 0);
    s = __builtin_amdgcn_mfma_f32_32x32x16_bf16(kf1, qf1, s, 0, 0, 0);
    // s[reg]: key = (reg&3) + 8*(reg>>2) + 4*hi, q = lane&31
    float p[16];
#pragma unroll
    for (int i = 0; i < 16; ++i) p[i] = fexp2(s[i]);
    {
      float t0 = (p[0] + p[1]) + (p[2] + p[3]);
      float t1 = (p[4] + p[5]) + (p[6] + p[7]);
      float t2 = (p[8] + p[9]) + (p[10] + p[11]);
      float t3 = (p[12] + p[13]) + (p[14] + p[15]);
      dsum += (t0 + t1) + (t2 + t3);
    }
    union { unsigned int ui[4]; s16x8 v; } pb0, pb1;
    pb0.ui[0] = cvt_pk_bf16(p[0], p[1]);    // keys {0,1}+4hi
    pb0.ui[1] = cvt_pk_bf16(p[2], p[3]);    // keys {2,3}+4hi
    pb0.ui[2] = cvt_pk_bf16(p[4], p[5]);    // keys {8,9}+4hi
    pb0.ui[3] = cvt_pk_bf16(p[6], p[7]);    // keys {10,11}+4hi
    pb1.ui[0] = cvt_pk_bf16(p[8], p[9]);    // keys {16,17}+4hi
    pb1.ui[1] = cvt_pk_bf16(p[10], p[11]);
    pb1.ui[2] = cvt_pk_bf16(p[12], p[13]);  // keys {24,25}+4hi
    pb1.ui[3] = cvt_pk_bf16(p[14], p[15]);
    s16x8 vf00 = *(const s16x8*)&Vls[buf][va00];
    s16x8 vf01 = *(const s16x8*)&Vls[buf][va01];
    s16x8 vf10 = *(const s16x8*)&Vls[buf][va10];
    s16x8 vf11 = *(const s16x8*)&Vls[buf][va11];
    accA = __builtin_amdgcn_mfma_f32_32x32x16_bf16(vf00, pb0.v, accA, 0, 0, 0);
    accA = __builtin_amdgcn_mfma_f32_32x32x16_bf16(vf01, pb1.v, accA, 0, 0, 0);
    accB = __builtin_amdgcn_mfma_f32_32x32x16_bf16(vf10, pb0.v, accB, 0, 0, 0);
    accB = __builtin_amdgcn_mfma_f32_32x32x16_bf16(vf11, pb1.v, accB, 0, 0, 0);
    if (pre) {
      int nb = buf ^ 1;
      *(uint4*)&Kls[nb][ke] = kld;
      *(uint4*)&Vls[nb][ve1] = make_uint4(vA.x, vA.y, vB.x, vB.y);
      *(uint4*)&Vls[nb][ve2] = make_uint4(vA.z, vA.w, vB.z, vB.w);
    }
  }

  // denominator: lane l holds sum over its 16 keys; partner (l^32) has the
  // complementary 16 of the same q. One cross-lane op per kernel.
  float total = dsum + __shfl_xor(dsum, 32, 64);
  float* outp = ws + OUTP_F;
  float* sump = ws + SUMP_F;
  if (!hi) atomicAdd(&sump[(size_t)b * NPTS + q], total);
#pragma unroll
  for (int reg = 0; reg < 16; ++reg) {
    int d = (reg & 3) + 8 * (reg >> 2) + 4 * hi;
    atomicAdd(&outp[((size_t)b * CH + d) * NPTS + q], accA[reg]);
    atomicAdd(&outp[((size_t)b * CH + 32 + d) * NPTS + q], accB[reg]);
  }
}

// ---------------- K3: merge — channel softmax + out_c GEMV + combine --------
__global__ __launch_bounds__(256) void merge_kernel(
    const float* __restrict__ x,
    const float* __restrict__ gamma_c, const float* __restrict__ gamma_p,
    const float* __restrict__ ws, float* __restrict__ out) {
  __shared__ float els[32 * EL_PITCH];
  int tid = threadIdx.x, l = tid & 63, w = tid >> 6;
  int b = blockIdx.y, zh = blockIdx.z;
  int n = blockIdx.x * 64 + l;

  const float* attg = ws + ATT_F + (size_t)b * CH * CH + (size_t)zh * 32 * CH;
  {
    int row = tid >> 3, col0 = (tid & 7) * 8;
    float4 t0 = *(const float4*)(attg + row * CH + col0);
    float4 t1 = *(const float4*)(attg + row * CH + col0 + 4);
    *(float4*)&els[row * EL_PITCH + col0] = t0;
    *(float4*)&els[row * EL_PITCH + col0 + 4] = t1;
  }
  __syncthreads();
  if (tid < 32) {
    float* e = els + tid * EL_PITCH;
    float m = -INFINITY;
#pragma unroll 8
    for (int k = 0; k < CH; ++k) m = fmaxf(m, e[k]);
    float s = 0.f;
#pragma unroll 8
    for (int k = 0; k < CH; ++k) { float p = __expf(e[k] - m); e[k] = p; s += p; }
    float inv = 1.f / s;
#pragma unroll 8
    for (int k = 0; k < CH; ++k) e[k] *= inv;
  }
  __syncthreads();

  const float* xb = x + (size_t)b * CH * NPTS;
  float xv[CH];
#pragma unroll
  for (int k = 0; k < CH; ++k) xv[k] = xb[(size_t)k * NPTS + n];
  const float* outp = ws + OUTP_F;
  const float* sump = ws + SUMP_F;
  float inv = 1.f / sump[(size_t)b * NPTS + n];
  float gcv = gamma_c[0], gpv = gamma_p[0];
  float* ob = out + (size_t)b * CH * NPTS;
#pragma unroll
  for (int cc = 0; cc < 8; ++cc) {
    int cl = w * 8 + cc;
    int c = zh * 32 + cl;
    const float* ar = els + cl * EL_PITCH;
    float a0 = 0.f, a1 = 0.f, a2 = 0.f, a3 = 0.f;
#pragma unroll
    for (int k = 0; k < CH; k += 4) {
      a0 += ar[k + 0] * xv[k + 0];
      a1 += ar[k + 1] * xv[k + 1];
      a2 += ar[k + 2] * xv[k + 2];
      a3 += ar[k + 3] * xv[k + 3];
    }
    float ocv = (a0 + a1) + (a2 + a3);
    float pv = outp[((size_t)b * CH + c) * NPTS + n] * inv;
    ob[(size_t)c * NPTS + n] = 2.f * xv[c] + gcv * ocv + gpv * pv;
  }
}

// ---------------- launcher --------------------------------------------------
extern "C" void kernel_launch(void* const* d_in, const int* in_sizes, int n_in,
                              void* d_out, int out_size, void* d_ws, size_t ws_size,
                              hipStream_t stream) {
  const float* x  = (const float*)d_in[0];
  const float* Wq = (const float*)d_in[1];
  const float* bq = (const float*)d_in[2];
  const float* Wk = (const float*)d_in[3];
  const float* bk = (const float*)d_in[4];
  const float* Wv = (const float*)d_in[5];
  const float* bv = (const float*)d_in[6];
  const float* gc = (const float*)d_in[7];
  const float* gp = (const float*)d_in[8];
  float* out = (float*)d_out;
  float* ws  = (float*)d_ws;

  (void)hipMemsetAsync(ws + ATT_F, 0, (size_t)BATCH * CH * CH * sizeof(float),
                       stream);
  qkv_energy_kernel<<<dim3(125, 2), 512, 0, stream>>>(x, Wq, bq, Wk, bk, Wv, bv, ws);
  flash_kernel<<<dim3(125, KSPLIT, 2), 128, 0, stream>>>(ws);
  merge_kernel<<<dim3(125, 2, 2), 256, 0, stream>>>(x, gc, gp, ws, out);
}